// Round 5
// baseline (188.735 us; speedup 1.0000x reference)
//
#include <hip/hip_runtime.h>
#include <math.h>

// ---------------------------------------------------------------------------
// EMD layer (Sinkhorn-OT logits) for MI355X.
// support: [32,512,8,8] f32, query: [256,512,8,8] f32 -> logits [256,32] f32.
//
// R16: marg FUSED into emd + 2-wave emd blocks.
//   - R15 null result proved marg was never the big DS cost. Instead, delete
//     it: each emd wave streams the exact U/V fragments whose channel-dots
//     with the pooled vectors ARE the a/b marginals. Fused per-kk VALU
//     (64 cvt+fma) computes dotA[n]=<U[:,n],Bp[w]>, dotB[n]=<V[:,n],Qp[q]>
//     alongside the sim MFMAs; un-normalized with the same f32 mu/nrm/S
//     formula as marg (summation-order drift only), rescaled intra-wave.
//     Removes marg kernel + launch gap; ws 22.7 -> 18.7 MB (less re-poison).
//   - emd blocks 256thr/4w -> 128thr/2w, per-wave LDS (18.4KB+1KB) => 8
//     blocks/CU, target 16 waves/CU (from ~11, Occupancy 34%): emd is
//     latency-bound (VALUBusy 50%, MfmaUtil 21%, both pipes half-idle).
//   - norm: pool stores now channel-major f32 Bp[w][512]/Qp[q][512].
//   Sinkhorn loop itself unchanged (R14 f32-M form).
// ---------------------------------------------------------------------------

#define DEV static __device__ __forceinline__

typedef _Float16 half8 __attribute__((ext_vector_type(8)));
typedef float floatx4 __attribute__((ext_vector_type(4)));

DEV float fast_rcp(float x) {
#if __has_builtin(__builtin_amdgcn_rcpf)
    return __builtin_amdgcn_rcpf(x);
#else
    return 1.0f / x;
#endif
}
DEV float fexp2(float x) {
#if __has_builtin(__builtin_amdgcn_exp2f)
    return __builtin_amdgcn_exp2f(x);
#else
    return exp2f(x);
#endif
}
DEV float flog2(float x) {
#if __has_builtin(__builtin_amdgcn_logf)
    return __builtin_amdgcn_logf(x);
#else
    return log2f(x);
#endif
}

#define K_SIM2M 28.853900817779268f    // 20/ln2 : M = 2^((sim-1)*K_SIM2M)
#define K_M2SIM 0.034657359027997264f  // 0.05*ln2 : sim = 1 + log2(M)*K_M2SIM
#define LDPH 72                        // padded LDS row stride (halves, emd)

// ------ K1: center+normalize over C -> fp16 FRAGMENT order, + pool stats ----
// 1024 threads: 16 waves. Fragment chunk (kk,t,slot) = channels
// kk*32+(slot>>4)*8..+8 of node t*16+(slot&15), at ((kk*4+t)*64+slot)*8 halves.
// Pools now stored channel-major: poolT[pidx*512 + c] (consumed by fused emd).
__global__ void __launch_bounds__(1024, 1)
norm_kernel(const float* __restrict__ support, const float* __restrict__ query,
            _Float16* __restrict__ Vht, _Float16* __restrict__ Uht,
            float* __restrict__ Bp, float* __restrict__ Qp,
            float* __restrict__ muA, float* __restrict__ nrmA,
            float* __restrict__ Ssc) {
    __shared__ float red1[16][64];
    __shared__ float red2[16][64];
    __shared__ float muL[64], invL[64];
    __shared__ float tile[128][65];

    int sid = blockIdx.x;             // 0..287
    const float* src;
    _Float16* dst;
    float* poolT;
    int pidx;
    if (sid < 32) {
        src = support + (size_t)sid * 32768; dst = Vht + (size_t)sid * 32768;
        poolT = Bp; pidx = sid;
    } else {
        src = query + (size_t)(sid - 32) * 32768; dst = Uht + (size_t)(sid - 32) * 32768;
        poolT = Qp; pidx = sid - 32;
    }

    int node = threadIdx.x & 63;
    int cq   = threadIdx.x >> 6;      // wave index 0..15

    // ---- stats pass: each wave handles 32 channels ----
    float s1 = 0.f, s2 = 0.f;
#pragma unroll 8
    for (int j = 0; j < 32; ++j) {
        int c = cq * 32 + j;
        float x = src[c * 64 + node];
        s1 += x; s2 += x * x;
        float ps = x;                  // pool: sum over the wave's 64 nodes
        ps += __shfl_xor(ps, 1);  ps += __shfl_xor(ps, 2);  ps += __shfl_xor(ps, 4);
        ps += __shfl_xor(ps, 8);  ps += __shfl_xor(ps, 16); ps += __shfl_xor(ps, 32);
        if (node == 0) poolT[(size_t)pidx * 512 + c] = ps * (1.0f / 64.0f);
    }
    red1[cq][node] = s1;
    red2[cq][node] = s2;
    __syncthreads();
    if (threadIdx.x < 64) {
        float t1 = 0.f, t2 = 0.f;
#pragma unroll
        for (int k = 0; k < 16; ++k) { t1 += red1[k][node]; t2 += red2[k][node]; }
        float mu  = t1 * (1.0f / 512.0f);
        float ss  = t2 - 512.0f * mu * mu;
        float nrm = fmaxf(sqrtf(fmaxf(ss, 0.0f)), 1e-8f);
        muL[node]  = mu;
        invL[node] = 1.0f / nrm;
        muA[sid * 64 + node]  = mu;
        nrmA[sid * 64 + node] = nrm;
        float sS = t1;                 // S = sum_c pool[c]
        sS += __shfl_xor(sS, 1);  sS += __shfl_xor(sS, 2);  sS += __shfl_xor(sS, 4);
        sS += __shfl_xor(sS, 8);  sS += __shfl_xor(sS, 16); sS += __shfl_xor(sS, 32);
        if (node == 0) Ssc[sid] = sS * (1.0f / 64.0f);
    }
    __syncthreads();

    // ---- normalize + fragment-order write, slab = 128 channels ----
    float mu = muL[node], inv = invL[node];
    for (int ch = 0; ch < 4; ++ch) {
#pragma unroll
        for (int j = 0; j < 8; ++j) {
            int cl = cq * 8 + j;       // 16 waves x 8 = 128 channels
            float x = src[(ch * 128 + cl) * 64 + node];
            tile[cl][node] = (x - mu) * inv;
        }
        __syncthreads();
        // 1024 fragment chunks per slab: exactly one per thread
        {
            int g    = threadIdx.x;    // kkl*256 + t*64 + slot
            int slot = g & 63;
            int t    = (g >> 6) & 3;
            int kkl  = g >> 8;
            int nd   = t * 16 + (slot & 15);
            int c8   = (kkl << 2) | (slot >> 4);
            half8 v;
#pragma unroll
            for (int i = 0; i < 8; ++i) v[i] = (_Float16)tile[c8 * 8 + i][nd];
            *(half8*)(dst + ((size_t)ch * 1024 + g) * 8) = v;
        }
        __syncthreads();
    }
}

// --- K2: FUSED MFMA sim + in-wave a/b marginals + Sinkhorn + logits ---------
// 2 waves/block, wave per (q,w). XCD-resident: blockIdx%8 = XCD, q-group.
// Per kk, alongside the 16 sim MFMAs, accumulate the channel-dots
//   dotA[node tm*16+lo16] += sum_j (f32)af[j] * Bp[w, kk*32+hi4*8+j]
//   dotB[node tn*16+lo16] += sum_j (f32)bf[j] * Qp[q, kk*32+hi4*8+j]
// (hi4 groups hold disjoint channel slices -> reduce via shfl 16,32).
__global__ void __launch_bounds__(128, 4)
emd_kernel(const _Float16* __restrict__ Uht, const _Float16* __restrict__ Vht,
           const float* __restrict__ Bp, const float* __restrict__ Qp,
           const float* __restrict__ muA, const float* __restrict__ nrmA,
           const float* __restrict__ Ssc, float* __restrict__ out) {
    __shared__ __align__(16) _Float16 T[2][64 * LDPH];   // 18,432 B
    __shared__ float dAB[2][128];                        //  1,024 B

    int x    = blockIdx.x & 7;
    int i    = blockIdx.x >> 3;       // 0..511: (qpair 16) x (w 32)
    int w    = i & 31;
    int wave = threadIdx.x >> 6;      // 0..1
    int lane = threadIdx.x & 63;
    int q    = x * 32 + (i >> 5) * 2 + wave;   // XCD x: q in [32x,32x+32)
    int lo16 = lane & 15;
    int hi4  = lane >> 4;
    int ig   = lane >> 3;
    int jg   = lane & 7;

    // ---- phase 1: sim tile via fp16 MFMA + fused marginal channel-dots ----
    floatx4 acc[4][4];
#pragma unroll
    for (int tm = 0; tm < 4; ++tm)
#pragma unroll
        for (int tn = 0; tn < 4; ++tn)
            acc[tm][tn] = (floatx4){0.f, 0.f, 0.f, 0.f};
    float accA[4] = {0.f, 0.f, 0.f, 0.f};
    float accB[4] = {0.f, 0.f, 0.f, 0.f};

    const _Float16* Abase = Uht + (size_t)q * 32768 + lane * 8;
    const _Float16* Bbase = Vht + (size_t)w * 32768 + lane * 8;
    const float* Bpw = Bp + (size_t)w * 512 + hi4 * 8;
    const float* Qpq = Qp + (size_t)q * 512 + hi4 * 8;
#pragma unroll 1
    for (int kk = 0; kk < 16; ++kk) {
        float4 wb0 = *(const float4*)(Bpw + kk * 32);
        float4 wb1 = *(const float4*)(Bpw + kk * 32 + 4);
        float4 wq0 = *(const float4*)(Qpq + kk * 32);
        float4 wq1 = *(const float4*)(Qpq + kk * 32 + 4);
        half8 bf[4];
#pragma unroll
        for (int t = 0; t < 4; ++t)
            bf[t] = *(const half8*)(Bbase + (size_t)(kk * 4 + t) * 512);
#pragma unroll
        for (int tn = 0; tn < 4; ++tn) {
            float s = accB[tn];
            s = fmaf((float)bf[tn][0], wq0.x, s); s = fmaf((float)bf[tn][1], wq0.y, s);
            s = fmaf((float)bf[tn][2], wq0.z, s); s = fmaf((float)bf[tn][3], wq0.w, s);
            s = fmaf((float)bf[tn][4], wq1.x, s); s = fmaf((float)bf[tn][5], wq1.y, s);
            s = fmaf((float)bf[tn][6], wq1.z, s); s = fmaf((float)bf[tn][7], wq1.w, s);
            accB[tn] = s;
        }
#pragma unroll
        for (int tm = 0; tm < 4; ++tm) {
            half8 af = *(const half8*)(Abase + (size_t)(kk * 4 + tm) * 512);
#pragma unroll
            for (int tn = 0; tn < 4; ++tn)
                acc[tm][tn] = __builtin_amdgcn_mfma_f32_16x16x32_f16(
                    af, bf[tn], acc[tm][tn], 0, 0, 0);
            float s = accA[tm];
            s = fmaf((float)af[0], wb0.x, s); s = fmaf((float)af[1], wb0.y, s);
            s = fmaf((float)af[2], wb0.z, s); s = fmaf((float)af[3], wb0.w, s);
            s = fmaf((float)af[4], wb1.x, s); s = fmaf((float)af[5], wb1.y, s);
            s = fmaf((float)af[6], wb1.z, s); s = fmaf((float)af[7], wb1.w, s);
            accA[tm] = s;
        }
    }

    // ---- marginal dots: reduce across hi4 channel-slices, park in LDS ----
    {
        float* dA = dAB[wave];
        float* dB = dAB[wave] + 64;
#pragma unroll
        for (int t = 0; t < 4; ++t) {
            accA[t] += __shfl_xor(accA[t], 16);
            accA[t] += __shfl_xor(accA[t], 32);
            accB[t] += __shfl_xor(accB[t], 16);
            accB[t] += __shfl_xor(accB[t], 32);
            dA[t * 16 + lo16] = accA[t];   // all hi4 write same value
            dB[t * 16 + lo16] = accB[t];
        }
    }

    // ---- wave-uniform tile max for the fp16 rescale ----
    float lmax = -2.0f;
#pragma unroll
    for (int tm = 0; tm < 4; ++tm)
#pragma unroll
        for (int tn = 0; tn < 4; ++tn)
#pragma unroll
            for (int r = 0; r < 4; ++r) lmax = fmaxf(lmax, acc[tm][tn][r]);
    lmax = fmaxf(lmax, __shfl_xor(lmax, 1));
    lmax = fmaxf(lmax, __shfl_xor(lmax, 2));
    lmax = fmaxf(lmax, __shfl_xor(lmax, 4));
    lmax = fmaxf(lmax, __shfl_xor(lmax, 8));
    lmax = fmaxf(lmax, __shfl_xor(lmax, 16));
    lmax = fmaxf(lmax, __shfl_xor(lmax, 32));
    float s0 = lmax;

    // ---- phase 2: exp -> f16 LDS (per-wave buffer) -> f32 Mf regs ----
    {
        _Float16* buf = T[wave];
#pragma unroll
        for (int tm = 0; tm < 4; ++tm)
#pragma unroll
            for (int tn = 0; tn < 4; ++tn)
#pragma unroll
                for (int r = 0; r < 4; ++r) {
                    int row = tm * 16 + hi4 * 4 + r;
                    int col = tn * 16 + lo16;
                    int sp  = (col & 7) ^ (row >> 3);
                    buf[row * LDPH + (col & ~7) + sp] =
                        (_Float16)fexp2((acc[tm][tn][r] - s0) * K_SIM2M);
                }
    }
    __syncthreads();
    float Mf[8][8];
    {
        const _Float16* buf = T[wave];
#pragma unroll
        for (int t = 0; t < 8; ++t) {
            half8 h = *(const half8*)(buf + (ig * 8 + (jg ^ t)) * LDPH + jg * 8);
#pragma unroll
            for (int c = 0; c < 8; ++c) Mf[t][c] = (float)h[c];
        }
    }

    // ---- in-wave a/b marginals (replaces the old marg kernel) ----
    int gp = q * 32 + w;
    float a_own, b_own;
    {
        const float* dA = dAB[wave];
        const float* dB = dAB[wave] + 64;
        float Sw = Ssc[w];
        float Sq = Ssc[32 + q];
        // a: q-node marginal at node = lane
        float muq = muA[(32 + q) * 64 + lane];
        float nrq = nrmA[(32 + q) * 64 + lane];
        float va = fmaxf(fmaf(muq, Sw, nrq * dA[lane]), 0.0f) + 0.001f;
        va += 1e-5f;
        float sa = va;
        sa += __shfl_xor(sa, 1);  sa += __shfl_xor(sa, 2);  sa += __shfl_xor(sa, 4);
        sa += __shfl_xor(sa, 8);  sa += __shfl_xor(sa, 16); sa += __shfl_xor(sa, 32);
        a_own = va * (64.0f / sa);
        // b: w-node marginal at node = jg*8+ig (lane bit-swap)
        int nb = ((lane & 7) << 3) | (lane >> 3);
        float muw = muA[w * 64 + nb];
        float nrw = nrmA[w * 64 + nb];
        float vb = fmaxf(fmaf(muw, Sq, nrw * dB[nb]), 0.0f) + 0.001f;
        vb += 1e-5f;
        float sb = vb;
        sb += __shfl_xor(sb, 1);  sb += __shfl_xor(sb, 2);  sb += __shfl_xor(sb, 4);
        sb += __shfl_xor(sb, 8);  sb += __shfl_xor(sb, 16); sb += __shfl_xor(sb, 32);
        b_own = vb * (64.0f / sb);
    }

    // ---- phase 3: Sinkhorn, reduce-scatter + all-gather, tol early exit ----
    float wvp[8];
#pragma unroll
    for (int s = 0; s < 8; ++s) wvp[s] = 1.0f;
    float q8[8];
    float w_prev = -1.f;

#pragma unroll 1
    for (int it = 0; it < 100; ++it) {
        float p[8];
#pragma unroll
        for (int t = 0; t < 8; ++t) {
            float s = Mf[t][0] * wvp[0];
#pragma unroll
            for (int c = 1; c < 8; ++c) s = fmaf(Mf[t][c], wvp[c], s);
            p[t] = s;
        }
        p[0] += __shfl_xor(p[4], 4); p[1] += __shfl_xor(p[5], 4);
        p[2] += __shfl_xor(p[6], 4); p[3] += __shfl_xor(p[7], 4);
        p[0] += __shfl_xor(p[2], 2); p[1] += __shfl_xor(p[3], 2);
        p[0] += __shfl_xor(p[1], 1);
        float z_own = a_own * fast_rcp(p[0]);
        q8[0] = z_own;
        q8[1] = __shfl_xor(q8[0], 1);
        q8[2] = __shfl_xor(q8[0], 2); q8[3] = __shfl_xor(q8[1], 2);
        q8[4] = __shfl_xor(q8[0], 4); q8[5] = __shfl_xor(q8[1], 4);
        q8[6] = __shfl_xor(q8[2], 4); q8[7] = __shfl_xor(q8[3], 4);
        float cp[8];
#pragma unroll
        for (int s = 0; s < 8; ++s) {
            float v = Mf[0][s] * q8[0];
#pragma unroll
            for (int t = 1; t < 8; ++t) v = fmaf(Mf[t][s], q8[t], v);
            cp[s] = v;
        }
        cp[0] += __shfl_xor(cp[4], 32); cp[1] += __shfl_xor(cp[5], 32);
        cp[2] += __shfl_xor(cp[6], 32); cp[3] += __shfl_xor(cp[7], 32);
        cp[0] += __shfl_xor(cp[2], 16); cp[1] += __shfl_xor(cp[3], 16);
        cp[0] += __shfl_xor(cp[1], 8);
        float w_own = b_own * fast_rcp(cp[0]);
        wvp[0] = w_own;
        wvp[1] = __shfl_xor(wvp[0], 8);
        wvp[2] = __shfl_xor(wvp[0], 16); wvp[3] = __shfl_xor(wvp[1], 16);
        wvp[4] = __shfl_xor(wvp[0], 32); wvp[5] = __shfl_xor(wvp[1], 32);
        wvp[6] = __shfl_xor(wvp[2], 32); wvp[7] = __shfl_xor(wvp[3], 32);
        // w stable across all 64 cols -> next z,w identical -> fixed point
        bool same = fabsf(w_own - w_prev) <= 1e-5f * w_own;
        w_prev = w_own;
        if (__all(same)) break;
    }

    // ---- phase 4: logits; sim = s0 + log2(M')*eps*ln2 ----
    float s = 0.f;
#pragma unroll
    for (int t = 0; t < 8; ++t)
#pragma unroll
        for (int c = 0; c < 8; ++c) {
            float m    = fmaxf(Mf[t][c], 1e-30f);
            float sim  = fmaf(flog2(m), K_M2SIM, s0);
            float flow = q8[t] * m * wvp[c];
            s = fmaf(sim, flow, s);
        }
    s += __shfl_xor(s, 1);  s += __shfl_xor(s, 2);  s += __shfl_xor(s, 4);
    s += __shfl_xor(s, 8);  s += __shfl_xor(s, 16); s += __shfl_xor(s, 32);
    if (lane == 0) out[gp] = s * 0.1953125f;   // 12.5/64
}

// ---------------------------------------------------------------------------
extern "C" void kernel_launch(void* const* d_in, const int* in_sizes, int n_in,
                              void* d_out, int out_size, void* d_ws, size_t ws_size,
                              hipStream_t stream) {
    (void)in_sizes; (void)n_in; (void)out_size; (void)ws_size;
    const float* support = (const float*)d_in[0];   // 32*512*64
    const float* query   = (const float*)d_in[1];   // 256*512*64

    char* ws = (char*)d_ws;
    _Float16* Uht = (_Float16*)ws;                  // 16 MB (fragment order)
    _Float16* Vht = Uht + 8388608;                  //  2 MB (fragment order)
    float* Bpp  = (float*)(Vht + 1048576);          // 64 KB  [32][512] channel-major
    float* Qpp  = Bpp + 16384;                      // 512 KB [256][512]
    float* muA  = Qpp + 131072;                     // 72 KB [288][64]
    float* nrmA = muA + 18432;                      // 72 KB
    float* Ssc  = nrmA + 18432;                     // ~1 KB [288]  (~18.7 MB total)

    norm_kernel<<<288, 1024, 0, stream>>>(support, query, Vht, Uht, Bpp, Qpp,
                                          muA, nrmA, Ssc);
    emd_kernel<<<4096, 128, 0, stream>>>(Uht, Vht, Bpp, Qpp, muA, nrmA, Ssc,
                                         (float*)d_out);
}

// Round 6
// 170.216 us; speedup vs baseline: 1.1088x; 1.1088x over previous
//
#include <hip/hip_runtime.h>
#include <math.h>

// ---------------------------------------------------------------------------
// EMD layer (Sinkhorn-OT logits) for MI355X.
// support: [32,512,8,8] f32, query: [256,512,8,8] f32 -> logits [256,32] f32.
//
// R17: marginal dots moved from VALU to MFMA. R16's fused marg cost 4k VALU
//      cyc/wave (128 cvt+fma per kk) inside the MFMA loop -> emd 67->105us.
//      The dots are rank-1 matmuls: dotA = mfma(af, bfp) with the pooled
//      support vector REPLICATED across B-columns (free: pooled vecs stored
//      channel-major f16, fragment load is lo16-independent), dotB =
//      mfma(afp, bf) with rows replicated. +8 MFMA/kk on a 13%-busy pipe,
//      zero VALU in the loop. Park via C-layout into the 1KB dAB LDS,
//      epilogue = R16. Pooled weights now f16 (small marginal drift,
//      Sinkhorn contracts it). Keeps R16's win: no marg kernel, ws 18.4MB.
//      norm: pool stores f16 channel-major. Sinkhorn = R14 f32-M form.
// ---------------------------------------------------------------------------

#define DEV static __device__ __forceinline__

typedef _Float16 half8 __attribute__((ext_vector_type(8)));
typedef float floatx4 __attribute__((ext_vector_type(4)));

DEV float fast_rcp(float x) {
#if __has_builtin(__builtin_amdgcn_rcpf)
    return __builtin_amdgcn_rcpf(x);
#else
    return 1.0f / x;
#endif
}
DEV float fexp2(float x) {
#if __has_builtin(__builtin_amdgcn_exp2f)
    return __builtin_amdgcn_exp2f(x);
#else
    return exp2f(x);
#endif
}
DEV float flog2(float x) {
#if __has_builtin(__builtin_amdgcn_logf)
    return __builtin_amdgcn_logf(x);
#else
    return log2f(x);
#endif
}

#define K_SIM2M 28.853900817779268f    // 20/ln2 : M = 2^((sim-1)*K_SIM2M)
#define K_M2SIM 0.034657359027997264f  // 0.05*ln2 : sim = 1 + log2(M)*K_M2SIM
#define LDPH 72                        // padded LDS row stride (halves, emd)

// ------ K1: center+normalize over C -> fp16 FRAGMENT order, + pool stats ----
// 1024 threads: 16 waves. Fragment chunk (kk,t,slot) = channels
// kk*32+(slot>>4)*8..+8 of node t*16+(slot&15), at ((kk*4+t)*64+slot)*8 halves.
// Pools stored channel-major f16: poolT[pidx*512 + c] (consumed as MFMA
// fragments by emd: address lo16-independent = replicated operand).
__global__ void __launch_bounds__(1024, 1)
norm_kernel(const float* __restrict__ support, const float* __restrict__ query,
            _Float16* __restrict__ Vht, _Float16* __restrict__ Uht,
            _Float16* __restrict__ Bp16, _Float16* __restrict__ Qp16,
            float* __restrict__ muA, float* __restrict__ nrmA,
            float* __restrict__ Ssc) {
    __shared__ float red1[16][64];
    __shared__ float red2[16][64];
    __shared__ float muL[64], invL[64];
    __shared__ float tile[128][65];

    int sid = blockIdx.x;             // 0..287
    const float* src;
    _Float16* dst;
    _Float16* poolT;
    int pidx;
    if (sid < 32) {
        src = support + (size_t)sid * 32768; dst = Vht + (size_t)sid * 32768;
        poolT = Bp16; pidx = sid;
    } else {
        src = query + (size_t)(sid - 32) * 32768; dst = Uht + (size_t)(sid - 32) * 32768;
        poolT = Qp16; pidx = sid - 32;
    }

    int node = threadIdx.x & 63;
    int cq   = threadIdx.x >> 6;      // wave index 0..15

    // ---- stats pass: each wave handles 32 channels ----
    float s1 = 0.f, s2 = 0.f;
#pragma unroll 8
    for (int j = 0; j < 32; ++j) {
        int c = cq * 32 + j;
        float x = src[c * 64 + node];
        s1 += x; s2 += x * x;
        float ps = x;                  // pool: sum over the wave's 64 nodes
        ps += __shfl_xor(ps, 1);  ps += __shfl_xor(ps, 2);  ps += __shfl_xor(ps, 4);
        ps += __shfl_xor(ps, 8);  ps += __shfl_xor(ps, 16); ps += __shfl_xor(ps, 32);
        if (node == 0) poolT[(size_t)pidx * 512 + c] = (_Float16)(ps * (1.0f / 64.0f));
    }
    red1[cq][node] = s1;
    red2[cq][node] = s2;
    __syncthreads();
    if (threadIdx.x < 64) {
        float t1 = 0.f, t2 = 0.f;
#pragma unroll
        for (int k = 0; k < 16; ++k) { t1 += red1[k][node]; t2 += red2[k][node]; }
        float mu  = t1 * (1.0f / 512.0f);
        float ss  = t2 - 512.0f * mu * mu;
        float nrm = fmaxf(sqrtf(fmaxf(ss, 0.0f)), 1e-8f);
        muL[node]  = mu;
        invL[node] = 1.0f / nrm;
        muA[sid * 64 + node]  = mu;
        nrmA[sid * 64 + node] = nrm;
        float sS = t1;                 // S = sum_c pool[c]
        sS += __shfl_xor(sS, 1);  sS += __shfl_xor(sS, 2);  sS += __shfl_xor(sS, 4);
        sS += __shfl_xor(sS, 8);  sS += __shfl_xor(sS, 16); sS += __shfl_xor(sS, 32);
        if (node == 0) Ssc[sid] = sS * (1.0f / 64.0f);
    }
    __syncthreads();

    // ---- normalize + fragment-order write, slab = 128 channels ----
    float mu = muL[node], inv = invL[node];
    for (int ch = 0; ch < 4; ++ch) {
#pragma unroll
        for (int j = 0; j < 8; ++j) {
            int cl = cq * 8 + j;       // 16 waves x 8 = 128 channels
            float x = src[(ch * 128 + cl) * 64 + node];
            tile[cl][node] = (x - mu) * inv;
        }
        __syncthreads();
        // 1024 fragment chunks per slab: exactly one per thread
        {
            int g    = threadIdx.x;    // kkl*256 + t*64 + slot
            int slot = g & 63;
            int t    = (g >> 6) & 3;
            int kkl  = g >> 8;
            int nd   = t * 16 + (slot & 15);
            int c8   = (kkl << 2) | (slot >> 4);
            half8 v;
#pragma unroll
            for (int i = 0; i < 8; ++i) v[i] = (_Float16)tile[c8 * 8 + i][nd];
            *(half8*)(dst + ((size_t)ch * 1024 + g) * 8) = v;
        }
        __syncthreads();
    }
}

// --- K2: FUSED MFMA sim + MFMA a/b marginals + Sinkhorn + logits ------------
// 2 waves/block, wave per (q,w). XCD-resident: blockIdx%8 = XCD, q-group.
// Marginal dots as rank-1 MFMAs with replicated pooled operands:
//   accPA[tm] = mfma(af[tm], bfp)  -> D[m][*] = dotA(node m), cols equal
//   accPB[tn] = mfma(afp,  bf[tn]) -> D[*][n] = dotB(node n), rows equal
__global__ void __launch_bounds__(128, 2)
emd_kernel(const _Float16* __restrict__ Uht, const _Float16* __restrict__ Vht,
           const _Float16* __restrict__ Bp16, const _Float16* __restrict__ Qp16,
           const float* __restrict__ muA, const float* __restrict__ nrmA,
           const float* __restrict__ Ssc, float* __restrict__ out) {
    __shared__ __align__(16) _Float16 T[2][64 * LDPH];   // 18,432 B
    __shared__ float dAB[2][128];                        //  1,024 B

    int x    = blockIdx.x & 7;
    int i    = blockIdx.x >> 3;       // 0..511: (qpair 16) x (w 32)
    int w    = i & 31;
    int wave = threadIdx.x >> 6;      // 0..1
    int lane = threadIdx.x & 63;
    int q    = x * 32 + (i >> 5) * 2 + wave;   // XCD x: q in [32x,32x+32)
    int lo16 = lane & 15;
    int hi4  = lane >> 4;
    int ig   = lane >> 3;
    int jg   = lane & 7;

    // ---- phase 1: sim tile + marginal rank-1 dots, all on the MFMA pipe ----
    floatx4 acc[4][4];
    floatx4 accPA[4], accPB[4];
#pragma unroll
    for (int tm = 0; tm < 4; ++tm) {
#pragma unroll
        for (int tn = 0; tn < 4; ++tn)
            acc[tm][tn] = (floatx4){0.f, 0.f, 0.f, 0.f};
        accPA[tm] = (floatx4){0.f, 0.f, 0.f, 0.f};
        accPB[tm] = (floatx4){0.f, 0.f, 0.f, 0.f};
    }

    const _Float16* Abase  = Uht + (size_t)q * 32768 + lane * 8;
    const _Float16* Bbase  = Vht + (size_t)w * 32768 + lane * 8;
    const _Float16* BpBase = Bp16 + (size_t)w * 512 + hi4 * 8;   // lo16-indep
    const _Float16* QpBase = Qp16 + (size_t)q * 512 + hi4 * 8;   // lo16-indep
#pragma unroll 1
    for (int kk = 0; kk < 16; ++kk) {
        half8 bfp = *(const half8*)(BpBase + kk * 32);   // pooled support frag
        half8 afp = *(const half8*)(QpBase + kk * 32);   // pooled query frag
        half8 bf[4];
#pragma unroll
        for (int t = 0; t < 4; ++t)
            bf[t] = *(const half8*)(Bbase + (size_t)(kk * 4 + t) * 512);
#pragma unroll
        for (int tn = 0; tn < 4; ++tn)
            accPB[tn] = __builtin_amdgcn_mfma_f32_16x16x32_f16(
                afp, bf[tn], accPB[tn], 0, 0, 0);
#pragma unroll
        for (int tm = 0; tm < 4; ++tm) {
            half8 af = *(const half8*)(Abase + (size_t)(kk * 4 + tm) * 512);
#pragma unroll
            for (int tn = 0; tn < 4; ++tn)
                acc[tm][tn] = __builtin_amdgcn_mfma_f32_16x16x32_f16(
                    af, bf[tn], acc[tm][tn], 0, 0, 0);
            accPA[tm] = __builtin_amdgcn_mfma_f32_16x16x32_f16(
                af, bfp, accPA[tm], 0, 0, 0);
        }
    }

    // ---- park marginal dots in LDS (C-layout -> node transpose) ----
    {
        float* dA = dAB[wave];
        float* dB = dAB[wave] + 64;
        if (lo16 == 0) {
            // accPA[tm][r] = dotA(node tm*16+hi4*4+r), cols equal
#pragma unroll
            for (int tm = 0; tm < 4; ++tm)
#pragma unroll
                for (int r = 0; r < 4; ++r)
                    dA[tm * 16 + hi4 * 4 + r] = accPA[tm][r];
        }
        if (hi4 == 0) {
            // accPB[tn][*] = dotB(node tn*16+lo16), rows equal
#pragma unroll
            for (int tn = 0; tn < 4; ++tn)
                dB[tn * 16 + lo16] = accPB[tn][0];
        }
    }

    // ---- wave-uniform tile max for the fp16 rescale ----
    float lmax = -2.0f;
#pragma unroll
    for (int tm = 0; tm < 4; ++tm)
#pragma unroll
        for (int tn = 0; tn < 4; ++tn)
#pragma unroll
            for (int r = 0; r < 4; ++r) lmax = fmaxf(lmax, acc[tm][tn][r]);
    lmax = fmaxf(lmax, __shfl_xor(lmax, 1));
    lmax = fmaxf(lmax, __shfl_xor(lmax, 2));
    lmax = fmaxf(lmax, __shfl_xor(lmax, 4));
    lmax = fmaxf(lmax, __shfl_xor(lmax, 8));
    lmax = fmaxf(lmax, __shfl_xor(lmax, 16));
    lmax = fmaxf(lmax, __shfl_xor(lmax, 32));
    float s0 = lmax;

    // ---- phase 2: exp -> f16 LDS (per-wave buffer) -> f32 Mf regs ----
    {
        _Float16* buf = T[wave];
#pragma unroll
        for (int tm = 0; tm < 4; ++tm)
#pragma unroll
            for (int tn = 0; tn < 4; ++tn)
#pragma unroll
                for (int r = 0; r < 4; ++r) {
                    int row = tm * 16 + hi4 * 4 + r;
                    int col = tn * 16 + lo16;
                    int sp  = (col & 7) ^ (row >> 3);
                    buf[row * LDPH + (col & ~7) + sp] =
                        (_Float16)fexp2((acc[tm][tn][r] - s0) * K_SIM2M);
                }
    }
    __syncthreads();
    float Mf[8][8];
    {
        const _Float16* buf = T[wave];
#pragma unroll
        for (int t = 0; t < 8; ++t) {
            half8 h = *(const half8*)(buf + (ig * 8 + (jg ^ t)) * LDPH + jg * 8);
#pragma unroll
            for (int c = 0; c < 8; ++c) Mf[t][c] = (float)h[c];
        }
    }

    // ---- in-wave a/b marginals ----
    int gp = q * 32 + w;
    float a_own, b_own;
    {
        const float* dA = dAB[wave];
        const float* dB = dAB[wave] + 64;
        float Sw = Ssc[w];
        float Sq = Ssc[32 + q];
        // a: q-node marginal at node = lane
        float muq = muA[(32 + q) * 64 + lane];
        float nrq = nrmA[(32 + q) * 64 + lane];
        float va = fmaxf(fmaf(muq, Sw, nrq * dA[lane]), 0.0f) + 0.001f;
        va += 1e-5f;
        float sa = va;
        sa += __shfl_xor(sa, 1);  sa += __shfl_xor(sa, 2);  sa += __shfl_xor(sa, 4);
        sa += __shfl_xor(sa, 8);  sa += __shfl_xor(sa, 16); sa += __shfl_xor(sa, 32);
        a_own = va * (64.0f / sa);
        // b: w-node marginal at node = jg*8+ig (lane bit-swap)
        int nb = ((lane & 7) << 3) | (lane >> 3);
        float muw = muA[w * 64 + nb];
        float nrw = nrmA[w * 64 + nb];
        float vb = fmaxf(fmaf(muw, Sq, nrw * dB[nb]), 0.0f) + 0.001f;
        vb += 1e-5f;
        float sb = vb;
        sb += __shfl_xor(sb, 1);  sb += __shfl_xor(sb, 2);  sb += __shfl_xor(sb, 4);
        sb += __shfl_xor(sb, 8);  sb += __shfl_xor(sb, 16); sb += __shfl_xor(sb, 32);
        b_own = vb * (64.0f / sb);
    }

    // ---- phase 3: Sinkhorn, reduce-scatter + all-gather, tol early exit ----
    float wvp[8];
#pragma unroll
    for (int s = 0; s < 8; ++s) wvp[s] = 1.0f;
    float q8[8];
    float w_prev = -1.f;

#pragma unroll 1
    for (int it = 0; it < 100; ++it) {
        float p[8];
#pragma unroll
        for (int t = 0; t < 8; ++t) {
            float s = Mf[t][0] * wvp[0];
#pragma unroll
            for (int c = 1; c < 8; ++c) s = fmaf(Mf[t][c], wvp[c], s);
            p[t] = s;
        }
        p[0] += __shfl_xor(p[4], 4); p[1] += __shfl_xor(p[5], 4);
        p[2] += __shfl_xor(p[6], 4); p[3] += __shfl_xor(p[7], 4);
        p[0] += __shfl_xor(p[2], 2); p[1] += __shfl_xor(p[3], 2);
        p[0] += __shfl_xor(p[1], 1);
        float z_own = a_own * fast_rcp(p[0]);
        q8[0] = z_own;
        q8[1] = __shfl_xor(q8[0], 1);
        q8[2] = __shfl_xor(q8[0], 2); q8[3] = __shfl_xor(q8[1], 2);
        q8[4] = __shfl_xor(q8[0], 4); q8[5] = __shfl_xor(q8[1], 4);
        q8[6] = __shfl_xor(q8[2], 4); q8[7] = __shfl_xor(q8[3], 4);
        float cp[8];
#pragma unroll
        for (int s = 0; s < 8; ++s) {
            float v = Mf[0][s] * q8[0];
#pragma unroll
            for (int t = 1; t < 8; ++t) v = fmaf(Mf[t][s], q8[t], v);
            cp[s] = v;
        }
        cp[0] += __shfl_xor(cp[4], 32); cp[1] += __shfl_xor(cp[5], 32);
        cp[2] += __shfl_xor(cp[6], 32); cp[3] += __shfl_xor(cp[7], 32);
        cp[0] += __shfl_xor(cp[2], 16); cp[1] += __shfl_xor(cp[3], 16);
        cp[0] += __shfl_xor(cp[1], 8);
        float w_own = b_own * fast_rcp(cp[0]);
        wvp[0] = w_own;
        wvp[1] = __shfl_xor(wvp[0], 8);
        wvp[2] = __shfl_xor(wvp[0], 16); wvp[3] = __shfl_xor(wvp[1], 16);
        wvp[4] = __shfl_xor(wvp[0], 32); wvp[5] = __shfl_xor(wvp[1], 32);
        wvp[6] = __shfl_xor(wvp[2], 32); wvp[7] = __shfl_xor(wvp[3], 32);
        // w stable across all 64 cols -> next z,w identical -> fixed point
        bool same = fabsf(w_own - w_prev) <= 1e-5f * w_own;
        w_prev = w_own;
        if (__all(same)) break;
    }

    // ---- phase 4: logits; sim = s0 + log2(M')*eps*ln2 ----
    float s = 0.f;
#pragma unroll
    for (int t = 0; t < 8; ++t)
#pragma unroll
        for (int c = 0; c < 8; ++c) {
            float m    = fmaxf(Mf[t][c], 1e-30f);
            float sim  = fmaf(flog2(m), K_M2SIM, s0);
            float flow = q8[t] * m * wvp[c];
            s = fmaf(sim, flow, s);
        }
    s += __shfl_xor(s, 1);  s += __shfl_xor(s, 2);  s += __shfl_xor(s, 4);
    s += __shfl_xor(s, 8);  s += __shfl_xor(s, 16); s += __shfl_xor(s, 32);
    if (lane == 0) out[gp] = s * 0.1953125f;   // 12.5/64
}

// ---------------------------------------------------------------------------
extern "C" void kernel_launch(void* const* d_in, const int* in_sizes, int n_in,
                              void* d_out, int out_size, void* d_ws, size_t ws_size,
                              hipStream_t stream) {
    (void)in_sizes; (void)n_in; (void)out_size; (void)ws_size;
    const float* support = (const float*)d_in[0];   // 32*512*64
    const float* query   = (const float*)d_in[1];   // 256*512*64

    char* ws = (char*)d_ws;
    _Float16* Uht  = (_Float16*)ws;                 // 16 MB (fragment order)
    _Float16* Vht  = Uht + 8388608;                 //  2 MB (fragment order)
    _Float16* Bp16 = Vht + 1048576;                 // 32 KB  [32][512] f16
    _Float16* Qp16 = Bp16 + 16384;                  // 256 KB [256][512] f16
    float* muA  = (float*)(Qp16 + 131072);          // 72 KB [288][64]
    float* nrmA = muA + 18432;                      // 72 KB
    float* Ssc  = nrmA + 18432;                     // ~1 KB [288]  (~18.4 MB total)

    norm_kernel<<<288, 1024, 0, stream>>>(support, query, Vht, Uht, Bp16, Qp16,
                                          muA, nrmA, Ssc);
    emd_kernel<<<4096, 128, 0, stream>>>(Uht, Vht, Bp16, Qp16, muA, nrmA, Ssc,
                                         (float*)d_out);
}

// Round 7
// 155.479 us; speedup vs baseline: 1.2139x; 1.0948x over previous
//
#include <hip/hip_runtime.h>
#include <math.h>

// ---------------------------------------------------------------------------
// EMD layer (Sinkhorn-OT logits) for MI355X.
// support: [32,512,8,8] f32, query: [256,512,8,8] f32 -> logits [256,32] f32.
//
// R18: marginals computed FROM the sim accumulator -- zero extra MFMA.
//      Since U,V are channel-centered (sum_c U[c,n] = 0), the pooled-raw
//      dots reduce algebraically to weighted row/col sums of sim:
//        dotA[n] = (1/64) sum_m nrm_w[m] * sim[n,m]
//        dotB[m] = (1/64) sum_n nrm_q[n] * sim[n,m]
//      R17's rank-1 MFMAs (+128 MFMA/pair, +32 AGPR, f16 pools) replaced by
//      ~130 fma + 72 shfl once per pair with f32 nrm weights. Regs drop to
//      ~120 -> __launch_bounds__(128,4) (cap 128, no R12-style starvation)
//      -> 4 waves/SIMD (was 3). Bp16/Qp16 deleted from ws and norm (pool
//      shuffle-reduce/stores gone). Sinkhorn/epilogue = R17 unchanged.
// ---------------------------------------------------------------------------

#define DEV static __device__ __forceinline__

typedef _Float16 half8 __attribute__((ext_vector_type(8)));
typedef float floatx4 __attribute__((ext_vector_type(4)));

DEV float fast_rcp(float x) {
#if __has_builtin(__builtin_amdgcn_rcpf)
    return __builtin_amdgcn_rcpf(x);
#else
    return 1.0f / x;
#endif
}
DEV float fexp2(float x) {
#if __has_builtin(__builtin_amdgcn_exp2f)
    return __builtin_amdgcn_exp2f(x);
#else
    return exp2f(x);
#endif
}
DEV float flog2(float x) {
#if __has_builtin(__builtin_amdgcn_logf)
    return __builtin_amdgcn_logf(x);
#else
    return log2f(x);
#endif
}

#define K_SIM2M 28.853900817779268f    // 20/ln2 : M = 2^((sim-1)*K_SIM2M)
#define K_M2SIM 0.034657359027997264f  // 0.05*ln2 : sim = 1 + log2(M)*K_M2SIM
#define LDPH 72                        // padded LDS row stride (halves, emd)

// ------ K1: center+normalize over C -> fp16 FRAGMENT order + stats ----------
// 1024 threads: 16 waves. Fragment chunk (kk,t,slot) = channels
// kk*32+(slot>>4)*8..+8 of node t*16+(slot&15), at ((kk*4+t)*64+slot)*8 halves.
__global__ void __launch_bounds__(1024, 1)
norm_kernel(const float* __restrict__ support, const float* __restrict__ query,
            _Float16* __restrict__ Vht, _Float16* __restrict__ Uht,
            float* __restrict__ muA, float* __restrict__ nrmA,
            float* __restrict__ Ssc) {
    __shared__ float red1[16][64];
    __shared__ float red2[16][64];
    __shared__ float muL[64], invL[64];
    __shared__ float tile[128][65];

    int sid = blockIdx.x;             // 0..287
    const float* src;
    _Float16* dst;
    if (sid < 32) {
        src = support + (size_t)sid * 32768; dst = Vht + (size_t)sid * 32768;
    } else {
        src = query + (size_t)(sid - 32) * 32768; dst = Uht + (size_t)(sid - 32) * 32768;
    }

    int node = threadIdx.x & 63;
    int cq   = threadIdx.x >> 6;      // wave index 0..15

    // ---- stats pass: each wave handles 32 channels ----
    float s1 = 0.f, s2 = 0.f;
#pragma unroll 8
    for (int j = 0; j < 32; ++j) {
        int c = cq * 32 + j;
        float x = src[c * 64 + node];
        s1 += x; s2 += x * x;
    }
    red1[cq][node] = s1;
    red2[cq][node] = s2;
    __syncthreads();
    if (threadIdx.x < 64) {
        float t1 = 0.f, t2 = 0.f;
#pragma unroll
        for (int k = 0; k < 16; ++k) { t1 += red1[k][node]; t2 += red2[k][node]; }
        float mu  = t1 * (1.0f / 512.0f);
        float ss  = t2 - 512.0f * mu * mu;
        float nrm = fmaxf(sqrtf(fmaxf(ss, 0.0f)), 1e-8f);
        muL[node]  = mu;
        invL[node] = 1.0f / nrm;
        muA[sid * 64 + node]  = mu;
        nrmA[sid * 64 + node] = nrm;
        float sS = t1;                 // S = sum_c pool[c] = (1/64) sum_{c,m} x
        sS += __shfl_xor(sS, 1);  sS += __shfl_xor(sS, 2);  sS += __shfl_xor(sS, 4);
        sS += __shfl_xor(sS, 8);  sS += __shfl_xor(sS, 16); sS += __shfl_xor(sS, 32);
        if (node == 0) Ssc[sid] = sS * (1.0f / 64.0f);
    }
    __syncthreads();

    // ---- normalize + fragment-order write, slab = 128 channels ----
    float mu = muL[node], inv = invL[node];
    for (int ch = 0; ch < 4; ++ch) {
#pragma unroll
        for (int j = 0; j < 8; ++j) {
            int cl = cq * 8 + j;       // 16 waves x 8 = 128 channels
            float x = src[(ch * 128 + cl) * 64 + node];
            tile[cl][node] = (x - mu) * inv;
        }
        __syncthreads();
        // 1024 fragment chunks per slab: exactly one per thread
        {
            int g    = threadIdx.x;    // kkl*256 + t*64 + slot
            int slot = g & 63;
            int t    = (g >> 6) & 3;
            int kkl  = g >> 8;
            int nd   = t * 16 + (slot & 15);
            int c8   = (kkl << 2) | (slot >> 4);
            half8 v;
#pragma unroll
            for (int i = 0; i < 8; ++i) v[i] = (_Float16)tile[c8 * 8 + i][nd];
            *(half8*)(dst + ((size_t)ch * 1024 + g) * 8) = v;
        }
        __syncthreads();
    }
}

// --- K2: FUSED MFMA sim + acc-derived a/b marginals + Sinkhorn + logits -----
// 2 waves/block, wave per (q,w). XCD-resident: blockIdx%8 = XCD, q-group.
// Marginal dots are nrm-weighted row/col sums of the sim acc (see header).
__global__ void __launch_bounds__(128, 4)
emd_kernel(const _Float16* __restrict__ Uht, const _Float16* __restrict__ Vht,
           const float* __restrict__ muA, const float* __restrict__ nrmA,
           const float* __restrict__ Ssc, float* __restrict__ out) {
    __shared__ __align__(16) _Float16 T[2][64 * LDPH];   // 18,432 B
    __shared__ float dAB[2][128];                        //  1,024 B

    int x    = blockIdx.x & 7;
    int i    = blockIdx.x >> 3;       // 0..511: (qpair 16) x (w 32)
    int w    = i & 31;
    int wave = threadIdx.x >> 6;      // 0..1
    int lane = threadIdx.x & 63;
    int q    = x * 32 + (i >> 5) * 2 + wave;   // XCD x: q in [32x,32x+32)
    int lo16 = lane & 15;
    int hi4  = lane >> 4;
    int ig   = lane >> 3;
    int jg   = lane & 7;

    // ---- phase 1: sim tile via fp16 MFMA, fragment-order loads ----
    floatx4 acc[4][4];
#pragma unroll
    for (int tm = 0; tm < 4; ++tm)
#pragma unroll
        for (int tn = 0; tn < 4; ++tn)
            acc[tm][tn] = (floatx4){0.f, 0.f, 0.f, 0.f};

    const _Float16* Abase = Uht + (size_t)q * 32768 + lane * 8;
    const _Float16* Bbase = Vht + (size_t)w * 32768 + lane * 8;
#pragma unroll 1
    for (int kk = 0; kk < 16; ++kk) {
        half8 bf[4];
#pragma unroll
        for (int t = 0; t < 4; ++t)
            bf[t] = *(const half8*)(Bbase + (size_t)(kk * 4 + t) * 512);
#pragma unroll
        for (int tm = 0; tm < 4; ++tm) {
            half8 af = *(const half8*)(Abase + (size_t)(kk * 4 + tm) * 512);
#pragma unroll
            for (int tn = 0; tn < 4; ++tn)
                acc[tm][tn] = __builtin_amdgcn_mfma_f32_16x16x32_f16(
                    af, bf[tn], acc[tm][tn], 0, 0, 0);
        }
    }

    // ---- marginal dots from the sim acc (weighted row/col sums) ----
    // dotA[n] = (1/64) sum_m nrm_w[m]*sim[n,m]  (rows n = query nodes)
    // dotB[m] = (1/64) sum_n nrm_q[n]*sim[n,m]  (cols m = support nodes)
    {
        float nw[4];
#pragma unroll
        for (int tn = 0; tn < 4; ++tn)
            nw[tn] = nrmA[w * 64 + tn * 16 + lo16];
        float4 nq[4];
#pragma unroll
        for (int tm = 0; tm < 4; ++tm)
            nq[tm] = *(const float4*)(nrmA + (32 + q) * 64 + tm * 16 + hi4 * 4);

        float pA[4][4];
#pragma unroll
        for (int tm = 0; tm < 4; ++tm)
#pragma unroll
            for (int r = 0; r < 4; ++r) {
                float s = acc[tm][0][r] * nw[0];
                s = fmaf(acc[tm][1][r], nw[1], s);
                s = fmaf(acc[tm][2][r], nw[2], s);
                s = fmaf(acc[tm][3][r], nw[3], s);
                s += __shfl_xor(s, 1); s += __shfl_xor(s, 2);
                s += __shfl_xor(s, 4); s += __shfl_xor(s, 8);
                pA[tm][r] = s;
            }
        float pB[4];
#pragma unroll
        for (int tn = 0; tn < 4; ++tn) {
            float s = acc[0][tn][0] * nq[0].x;
            s = fmaf(acc[0][tn][1], nq[0].y, s);
            s = fmaf(acc[0][tn][2], nq[0].z, s);
            s = fmaf(acc[0][tn][3], nq[0].w, s);
#pragma unroll
            for (int tm = 1; tm < 4; ++tm) {
                s = fmaf(acc[tm][tn][0], nq[tm].x, s);
                s = fmaf(acc[tm][tn][1], nq[tm].y, s);
                s = fmaf(acc[tm][tn][2], nq[tm].z, s);
                s = fmaf(acc[tm][tn][3], nq[tm].w, s);
            }
            s += __shfl_xor(s, 16); s += __shfl_xor(s, 32);
            pB[tn] = s;
        }
        float* dA = dAB[wave];
        float* dB = dAB[wave] + 64;
        if (lo16 == 0) {
#pragma unroll
            for (int tm = 0; tm < 4; ++tm)
#pragma unroll
                for (int r = 0; r < 4; ++r)
                    dA[tm * 16 + hi4 * 4 + r] = pA[tm][r] * 0.015625f;
        }
        if (hi4 == 0) {
#pragma unroll
            for (int tn = 0; tn < 4; ++tn)
                dB[tn * 16 + lo16] = pB[tn] * 0.015625f;
        }
    }

    // ---- wave-uniform tile max for the fp16 rescale ----
    float lmax = -2.0f;
#pragma unroll
    for (int tm = 0; tm < 4; ++tm)
#pragma unroll
        for (int tn = 0; tn < 4; ++tn)
#pragma unroll
            for (int r = 0; r < 4; ++r) lmax = fmaxf(lmax, acc[tm][tn][r]);
    lmax = fmaxf(lmax, __shfl_xor(lmax, 1));
    lmax = fmaxf(lmax, __shfl_xor(lmax, 2));
    lmax = fmaxf(lmax, __shfl_xor(lmax, 4));
    lmax = fmaxf(lmax, __shfl_xor(lmax, 8));
    lmax = fmaxf(lmax, __shfl_xor(lmax, 16));
    lmax = fmaxf(lmax, __shfl_xor(lmax, 32));
    float s0 = lmax;

    // ---- phase 2: exp -> f16 LDS (per-wave buffer) -> f32 Mf regs ----
    {
        _Float16* buf = T[wave];
#pragma unroll
        for (int tm = 0; tm < 4; ++tm)
#pragma unroll
            for (int tn = 0; tn < 4; ++tn)
#pragma unroll
                for (int r = 0; r < 4; ++r) {
                    int row = tm * 16 + hi4 * 4 + r;
                    int col = tn * 16 + lo16;
                    int sp  = (col & 7) ^ (row >> 3);
                    buf[row * LDPH + (col & ~7) + sp] =
                        (_Float16)fexp2((acc[tm][tn][r] - s0) * K_SIM2M);
                }
    }
    __syncthreads();
    float Mf[8][8];
    {
        const _Float16* buf = T[wave];
#pragma unroll
        for (int t = 0; t < 8; ++t) {
            half8 h = *(const half8*)(buf + (ig * 8 + (jg ^ t)) * LDPH + jg * 8);
#pragma unroll
            for (int c = 0; c < 8; ++c) Mf[t][c] = (float)h[c];
        }
    }

    // ---- in-wave a/b marginals ----
    int gp = q * 32 + w;
    float a_own, b_own;
    {
        const float* dA = dAB[wave];
        const float* dB = dAB[wave] + 64;
        float Sw = Ssc[w];
        float Sq = Ssc[32 + q];
        // a: q-node marginal at node = lane
        float muq = muA[(32 + q) * 64 + lane];
        float nrq = nrmA[(32 + q) * 64 + lane];
        float va = fmaxf(fmaf(muq, Sw, nrq * dA[lane]), 0.0f) + 0.001f;
        va += 1e-5f;
        float sa = va;
        sa += __shfl_xor(sa, 1);  sa += __shfl_xor(sa, 2);  sa += __shfl_xor(sa, 4);
        sa += __shfl_xor(sa, 8);  sa += __shfl_xor(sa, 16); sa += __shfl_xor(sa, 32);
        a_own = va * (64.0f / sa);
        // b: w-node marginal at node = jg*8+ig (lane bit-swap)
        int nb = ((lane & 7) << 3) | (lane >> 3);
        float muw = muA[w * 64 + nb];
        float nrw = nrmA[w * 64 + nb];
        float vb = fmaxf(fmaf(muw, Sq, nrw * dB[nb]), 0.0f) + 0.001f;
        vb += 1e-5f;
        float sb = vb;
        sb += __shfl_xor(sb, 1);  sb += __shfl_xor(sb, 2);  sb += __shfl_xor(sb, 4);
        sb += __shfl_xor(sb, 8);  sb += __shfl_xor(sb, 16); sb += __shfl_xor(sb, 32);
        b_own = vb * (64.0f / sb);
    }

    // ---- phase 3: Sinkhorn, reduce-scatter + all-gather, tol early exit ----
    float wvp[8];
#pragma unroll
    for (int s = 0; s < 8; ++s) wvp[s] = 1.0f;
    float q8[8];
    float w_prev = -1.f;

#pragma unroll 1
    for (int it = 0; it < 100; ++it) {
        float p[8];
#pragma unroll
        for (int t = 0; t < 8; ++t) {
            float s = Mf[t][0] * wvp[0];
#pragma unroll
            for (int c = 1; c < 8; ++c) s = fmaf(Mf[t][c], wvp[c], s);
            p[t] = s;
        }
        p[0] += __shfl_xor(p[4], 4); p[1] += __shfl_xor(p[5], 4);
        p[2] += __shfl_xor(p[6], 4); p[3] += __shfl_xor(p[7], 4);
        p[0] += __shfl_xor(p[2], 2); p[1] += __shfl_xor(p[3], 2);
        p[0] += __shfl_xor(p[1], 1);
        float z_own = a_own * fast_rcp(p[0]);
        q8[0] = z_own;
        q8[1] = __shfl_xor(q8[0], 1);
        q8[2] = __shfl_xor(q8[0], 2); q8[3] = __shfl_xor(q8[1], 2);
        q8[4] = __shfl_xor(q8[0], 4); q8[5] = __shfl_xor(q8[1], 4);
        q8[6] = __shfl_xor(q8[2], 4); q8[7] = __shfl_xor(q8[3], 4);
        float cp[8];
#pragma unroll
        for (int s = 0; s < 8; ++s) {
            float v = Mf[0][s] * q8[0];
#pragma unroll
            for (int t = 1; t < 8; ++t) v = fmaf(Mf[t][s], q8[t], v);
            cp[s] = v;
        }
        cp[0] += __shfl_xor(cp[4], 32); cp[1] += __shfl_xor(cp[5], 32);
        cp[2] += __shfl_xor(cp[6], 32); cp[3] += __shfl_xor(cp[7], 32);
        cp[0] += __shfl_xor(cp[2], 16); cp[1] += __shfl_xor(cp[3], 16);
        cp[0] += __shfl_xor(cp[1], 8);
        float w_own = b_own * fast_rcp(cp[0]);
        wvp[0] = w_own;
        wvp[1] = __shfl_xor(wvp[0], 8);
        wvp[2] = __shfl_xor(wvp[0], 16); wvp[3] = __shfl_xor(wvp[1], 16);
        wvp[4] = __shfl_xor(wvp[0], 32); wvp[5] = __shfl_xor(wvp[1], 32);
        wvp[6] = __shfl_xor(wvp[2], 32); wvp[7] = __shfl_xor(wvp[3], 32);
        // w stable across all 64 cols -> next z,w identical -> fixed point
        bool same = fabsf(w_own - w_prev) <= 1e-5f * w_own;
        w_prev = w_own;
        if (__all(same)) break;
    }

    // ---- phase 4: logits; sim = s0 + log2(M')*eps*ln2 ----
    float s = 0.f;
#pragma unroll
    for (int t = 0; t < 8; ++t)
#pragma unroll
        for (int c = 0; c < 8; ++c) {
            float m    = fmaxf(Mf[t][c], 1e-30f);
            float sim  = fmaf(flog2(m), K_M2SIM, s0);
            float flow = q8[t] * m * wvp[c];
            s = fmaf(sim, flow, s);
        }
    s += __shfl_xor(s, 1);  s += __shfl_xor(s, 2);  s += __shfl_xor(s, 4);
    s += __shfl_xor(s, 8);  s += __shfl_xor(s, 16); s += __shfl_xor(s, 32);
    if (lane == 0) out[gp] = s * 0.1953125f;   // 12.5/64
}

// ---------------------------------------------------------------------------
extern "C" void kernel_launch(void* const* d_in, const int* in_sizes, int n_in,
                              void* d_out, int out_size, void* d_ws, size_t ws_size,
                              hipStream_t stream) {
    (void)in_sizes; (void)n_in; (void)out_size; (void)ws_size;
    const float* support = (const float*)d_in[0];   // 32*512*64
    const float* query   = (const float*)d_in[1];   // 256*512*64

    char* ws = (char*)d_ws;
    _Float16* Uht  = (_Float16*)ws;                 // 16 MB (fragment order)
    _Float16* Vht  = Uht + 8388608;                 //  2 MB (fragment order)
    float* muA  = (float*)(Vht + 1048576);          // 72 KB [288][64]
    float* nrmA = muA + 18432;                      // 72 KB
    float* Ssc  = nrmA + 18432;                     // ~1 KB [288]  (~18.1 MB total)

    norm_kernel<<<288, 1024, 0, stream>>>(support, query, Vht, Uht,
                                          muA, nrmA, Ssc);
    emd_kernel<<<4096, 128, 0, stream>>>(Uht, Vht, muA, nrmA, Ssc,
                                         (float*)d_out);
}

// Round 8
// 149.831 us; speedup vs baseline: 1.2597x; 1.0377x over previous
//
#include <hip/hip_runtime.h>
#include <math.h>

// ---------------------------------------------------------------------------
// EMD layer (Sinkhorn-OT logits) for MI355X.
// support: [32,512,8,8] f32, query: [256,512,8,8] f32 -> logits [256,32] f32.
//
// R19: three emd changes on top of R18 (acc-derived marginals kept):
//  1. Sinkhorn dots on v_pk_fma_f32 (packed 2xf32, full-rate VOP3P): M as
//     float2[8][4]; p-dot = 4 pk_fma + hadd, cp-dot pairs over COLUMNS so
//     the same packed layout works with a broadcast {q8,q8} operand.
//     ~150 -> ~110 VALU/iter on an issue-bound loop.
//  2. 4 waves/block sharing one w (R14 geometry): V fragment loads L1-shared
//     x4 -> phase-1 L2 streaming ~128KB -> ~80KB per wave.
//  3. __syncthreads REMOVED: T and dAB are wave-private since R14; in-wave
//     LDS RAW needs only compiler lgkmcnt. Waves fully decoupled (ragged
//     Sinkhorn exit no longer couples).
//  norm unchanged. LDS 4x9216+2048 = 38.9KB -> 4 blocks/CU (16 waves/CU).
// ---------------------------------------------------------------------------

#define DEV static __device__ __forceinline__

typedef _Float16 half8 __attribute__((ext_vector_type(8)));
typedef float floatx4 __attribute__((ext_vector_type(4)));
typedef float floatx2 __attribute__((ext_vector_type(2)));

DEV float fast_rcp(float x) {
#if __has_builtin(__builtin_amdgcn_rcpf)
    return __builtin_amdgcn_rcpf(x);
#else
    return 1.0f / x;
#endif
}
DEV float fexp2(float x) {
#if __has_builtin(__builtin_amdgcn_exp2f)
    return __builtin_amdgcn_exp2f(x);
#else
    return exp2f(x);
#endif
}
DEV float flog2(float x) {
#if __has_builtin(__builtin_amdgcn_logf)
    return __builtin_amdgcn_logf(x);
#else
    return log2f(x);
#endif
}
DEV floatx2 pk_mul(floatx2 a, floatx2 b) {
    floatx2 d;
    asm("v_pk_mul_f32 %0, %1, %2" : "=v"(d) : "v"(a), "v"(b));
    return d;
}
DEV floatx2 pk_fma(floatx2 a, floatx2 b, floatx2 c) {
    floatx2 d;
    asm("v_pk_fma_f32 %0, %1, %2, %3" : "=v"(d) : "v"(a), "v"(b), "v"(c));
    return d;
}

#define K_SIM2M 28.853900817779268f    // 20/ln2 : M = 2^((sim-1)*K_SIM2M)
#define K_M2SIM 0.034657359027997264f  // 0.05*ln2 : sim = 1 + log2(M)*K_M2SIM
#define LDPH 72                        // padded LDS row stride (halves, emd)

// ------ K1: center+normalize over C -> fp16 FRAGMENT order + stats ----------
// 1024 threads: 16 waves. Fragment chunk (kk,t,slot) = channels
// kk*32+(slot>>4)*8..+8 of node t*16+(slot&15), at ((kk*4+t)*64+slot)*8 halves.
__global__ void __launch_bounds__(1024, 1)
norm_kernel(const float* __restrict__ support, const float* __restrict__ query,
            _Float16* __restrict__ Vht, _Float16* __restrict__ Uht,
            float* __restrict__ muA, float* __restrict__ nrmA,
            float* __restrict__ Ssc) {
    __shared__ float red1[16][64];
    __shared__ float red2[16][64];
    __shared__ float muL[64], invL[64];
    __shared__ float tile[128][65];

    int sid = blockIdx.x;             // 0..287
    const float* src;
    _Float16* dst;
    if (sid < 32) {
        src = support + (size_t)sid * 32768; dst = Vht + (size_t)sid * 32768;
    } else {
        src = query + (size_t)(sid - 32) * 32768; dst = Uht + (size_t)(sid - 32) * 32768;
    }

    int node = threadIdx.x & 63;
    int cq   = threadIdx.x >> 6;      // wave index 0..15

    // ---- stats pass: each wave handles 32 channels ----
    float s1 = 0.f, s2 = 0.f;
#pragma unroll 8
    for (int j = 0; j < 32; ++j) {
        int c = cq * 32 + j;
        float x = src[c * 64 + node];
        s1 += x; s2 += x * x;
    }
    red1[cq][node] = s1;
    red2[cq][node] = s2;
    __syncthreads();
    if (threadIdx.x < 64) {
        float t1 = 0.f, t2 = 0.f;
#pragma unroll
        for (int k = 0; k < 16; ++k) { t1 += red1[k][node]; t2 += red2[k][node]; }
        float mu  = t1 * (1.0f / 512.0f);
        float ss  = t2 - 512.0f * mu * mu;
        float nrm = fmaxf(sqrtf(fmaxf(ss, 0.0f)), 1e-8f);
        muL[node]  = mu;
        invL[node] = 1.0f / nrm;
        muA[sid * 64 + node]  = mu;
        nrmA[sid * 64 + node] = nrm;
        float sS = t1;                 // S = sum_c pool[c] = (1/64) sum_{c,m} x
        sS += __shfl_xor(sS, 1);  sS += __shfl_xor(sS, 2);  sS += __shfl_xor(sS, 4);
        sS += __shfl_xor(sS, 8);  sS += __shfl_xor(sS, 16); sS += __shfl_xor(sS, 32);
        if (node == 0) Ssc[sid] = sS * (1.0f / 64.0f);
    }
    __syncthreads();

    // ---- normalize + fragment-order write, slab = 128 channels ----
    float mu = muL[node], inv = invL[node];
    for (int ch = 0; ch < 4; ++ch) {
#pragma unroll
        for (int j = 0; j < 8; ++j) {
            int cl = cq * 8 + j;       // 16 waves x 8 = 128 channels
            float x = src[(ch * 128 + cl) * 64 + node];
            tile[cl][node] = (x - mu) * inv;
        }
        __syncthreads();
        // 1024 fragment chunks per slab: exactly one per thread
        {
            int g    = threadIdx.x;    // kkl*256 + t*64 + slot
            int slot = g & 63;
            int t    = (g >> 6) & 3;
            int kkl  = g >> 8;
            int nd   = t * 16 + (slot & 15);
            int c8   = (kkl << 2) | (slot >> 4);
            half8 v;
#pragma unroll
            for (int i = 0; i < 8; ++i) v[i] = (_Float16)tile[c8 * 8 + i][nd];
            *(half8*)(dst + ((size_t)ch * 1024 + g) * 8) = v;
        }
        __syncthreads();
    }
}

// --- K2: FUSED MFMA sim + acc-derived a/b marginals + pk-Sinkhorn + logits --
// 4 waves/block sharing one w (V loads L1-shared), wave-private LDS, no
// barriers. XCD-resident: blockIdx%8 = XCD owns q in [32x, 32x+32).
__global__ void __launch_bounds__(256, 4)
emd_kernel(const _Float16* __restrict__ Uht, const _Float16* __restrict__ Vht,
           const float* __restrict__ muA, const float* __restrict__ nrmA,
           const float* __restrict__ Ssc, float* __restrict__ out) {
    __shared__ __align__(16) _Float16 T[4][64 * LDPH];   // 36,864 B
    __shared__ float dAB[4][128];                        //  2,048 B

    int x    = blockIdx.x & 7;
    int i    = blockIdx.x >> 3;       // 0..255: (qquad 8) x (w 32)
    int w    = i & 31;
    int wave = threadIdx.x >> 6;      // 0..3
    int lane = threadIdx.x & 63;
    int q    = x * 32 + (i >> 5) * 4 + wave;   // XCD x: q in [32x,32x+32)
    int lo16 = lane & 15;
    int hi4  = lane >> 4;
    int ig   = lane >> 3;
    int jg   = lane & 7;

    // ---- phase 1: sim tile via fp16 MFMA, fragment-order loads ----
    floatx4 acc[4][4];
#pragma unroll
    for (int tm = 0; tm < 4; ++tm)
#pragma unroll
        for (int tn = 0; tn < 4; ++tn)
            acc[tm][tn] = (floatx4){0.f, 0.f, 0.f, 0.f};

    const _Float16* Abase = Uht + (size_t)q * 32768 + lane * 8;
    const _Float16* Bbase = Vht + (size_t)w * 32768 + lane * 8;
#pragma unroll 1
    for (int kk = 0; kk < 16; ++kk) {
        half8 bf[4];
#pragma unroll
        for (int t = 0; t < 4; ++t)
            bf[t] = *(const half8*)(Bbase + (size_t)(kk * 4 + t) * 512);
#pragma unroll
        for (int tm = 0; tm < 4; ++tm) {
            half8 af = *(const half8*)(Abase + (size_t)(kk * 4 + tm) * 512);
#pragma unroll
            for (int tn = 0; tn < 4; ++tn)
                acc[tm][tn] = __builtin_amdgcn_mfma_f32_16x16x32_f16(
                    af, bf[tn], acc[tm][tn], 0, 0, 0);
        }
    }

    // ---- marginal dots from the sim acc (weighted row/col sums) ----
    // dotA[n] = (1/64) sum_m nrm_w[m]*sim[n,m]; dotB[m] = (1/64) sum_n nrm_q[n]*sim[n,m]
    {
        float nw[4];
#pragma unroll
        for (int tn = 0; tn < 4; ++tn)
            nw[tn] = nrmA[w * 64 + tn * 16 + lo16];
        float4 nq[4];
#pragma unroll
        for (int tm = 0; tm < 4; ++tm)
            nq[tm] = *(const float4*)(nrmA + (32 + q) * 64 + tm * 16 + hi4 * 4);

        float pA[4][4];
#pragma unroll
        for (int tm = 0; tm < 4; ++tm)
#pragma unroll
            for (int r = 0; r < 4; ++r) {
                float s = acc[tm][0][r] * nw[0];
                s = fmaf(acc[tm][1][r], nw[1], s);
                s = fmaf(acc[tm][2][r], nw[2], s);
                s = fmaf(acc[tm][3][r], nw[3], s);
                s += __shfl_xor(s, 1); s += __shfl_xor(s, 2);
                s += __shfl_xor(s, 4); s += __shfl_xor(s, 8);
                pA[tm][r] = s;
            }
        float pB[4];
#pragma unroll
        for (int tn = 0; tn < 4; ++tn) {
            float s = acc[0][tn][0] * nq[0].x;
            s = fmaf(acc[0][tn][1], nq[0].y, s);
            s = fmaf(acc[0][tn][2], nq[0].z, s);
            s = fmaf(acc[0][tn][3], nq[0].w, s);
#pragma unroll
            for (int tm = 1; tm < 4; ++tm) {
                s = fmaf(acc[tm][tn][0], nq[tm].x, s);
                s = fmaf(acc[tm][tn][1], nq[tm].y, s);
                s = fmaf(acc[tm][tn][2], nq[tm].z, s);
                s = fmaf(acc[tm][tn][3], nq[tm].w, s);
            }
            s += __shfl_xor(s, 16); s += __shfl_xor(s, 32);
            pB[tn] = s;
        }
        float* dA = dAB[wave];
        float* dB = dAB[wave] + 64;
        if (lo16 == 0) {
#pragma unroll
            for (int tm = 0; tm < 4; ++tm)
#pragma unroll
                for (int r = 0; r < 4; ++r)
                    dA[tm * 16 + hi4 * 4 + r] = pA[tm][r] * 0.015625f;
        }
        if (hi4 == 0) {
#pragma unroll
            for (int tn = 0; tn < 4; ++tn)
                dB[tn * 16 + lo16] = pB[tn] * 0.015625f;
        }
    }

    // ---- wave-uniform tile max for the fp16 rescale ----
    float lmax = -2.0f;
#pragma unroll
    for (int tm = 0; tm < 4; ++tm)
#pragma unroll
        for (int tn = 0; tn < 4; ++tn)
#pragma unroll
            for (int r = 0; r < 4; ++r) lmax = fmaxf(lmax, acc[tm][tn][r]);
    lmax = fmaxf(lmax, __shfl_xor(lmax, 1));
    lmax = fmaxf(lmax, __shfl_xor(lmax, 2));
    lmax = fmaxf(lmax, __shfl_xor(lmax, 4));
    lmax = fmaxf(lmax, __shfl_xor(lmax, 8));
    lmax = fmaxf(lmax, __shfl_xor(lmax, 16));
    lmax = fmaxf(lmax, __shfl_xor(lmax, 32));
    float s0 = lmax;

    // ---- phase 2: exp -> f16 LDS (wave-private, NO barrier) -> packed M ----
    {
        _Float16* buf = T[wave];
#pragma unroll
        for (int tm = 0; tm < 4; ++tm)
#pragma unroll
            for (int tn = 0; tn < 4; ++tn)
#pragma unroll
                for (int r = 0; r < 4; ++r) {
                    int row = tm * 16 + hi4 * 4 + r;
                    int col = tn * 16 + lo16;
                    int sp  = (col & 7) ^ (row >> 3);
                    buf[row * LDPH + (col & ~7) + sp] =
                        (_Float16)fexp2((acc[tm][tn][r] - s0) * K_SIM2M);
                }
    }
    floatx2 Mp[8][4];
    {
        const _Float16* buf = T[wave];
#pragma unroll
        for (int t = 0; t < 8; ++t) {
            half8 h = *(const half8*)(buf + (ig * 8 + (jg ^ t)) * LDPH + jg * 8);
#pragma unroll
            for (int j = 0; j < 4; ++j)
                Mp[t][j] = (floatx2){(float)h[2 * j], (float)h[2 * j + 1]};
        }
    }

    // ---- in-wave a/b marginals ----
    int gp = q * 32 + w;
    float a_own, b_own;
    {
        const float* dA = dAB[wave];
        const float* dB = dAB[wave] + 64;
        float Sw = Ssc[w];
        float Sq = Ssc[32 + q];
        // a: q-node marginal at node = lane
        float muq = muA[(32 + q) * 64 + lane];
        float nrq = nrmA[(32 + q) * 64 + lane];
        float va = fmaxf(fmaf(muq, Sw, nrq * dA[lane]), 0.0f) + 0.001f;
        va += 1e-5f;
        float sa = va;
        sa += __shfl_xor(sa, 1);  sa += __shfl_xor(sa, 2);  sa += __shfl_xor(sa, 4);
        sa += __shfl_xor(sa, 8);  sa += __shfl_xor(sa, 16); sa += __shfl_xor(sa, 32);
        a_own = va * (64.0f / sa);
        // b: w-node marginal at node = jg*8+ig (lane bit-swap)
        int nb = ((lane & 7) << 3) | (lane >> 3);
        float muw = muA[w * 64 + nb];
        float nrw = nrmA[w * 64 + nb];
        float vb = fmaxf(fmaf(muw, Sq, nrw * dB[nb]), 0.0f) + 0.001f;
        vb += 1e-5f;
        float sb = vb;
        sb += __shfl_xor(sb, 1);  sb += __shfl_xor(sb, 2);  sb += __shfl_xor(sb, 4);
        sb += __shfl_xor(sb, 8);  sb += __shfl_xor(sb, 16); sb += __shfl_xor(sb, 32);
        b_own = vb * (64.0f / sb);
    }

    // ---- phase 3: Sinkhorn on v_pk_fma_f32, tol early exit ----
    floatx2 wv2[4];
#pragma unroll
    for (int j = 0; j < 4; ++j) wv2[j] = (floatx2){1.f, 1.f};
    float q8[8];
    float w_prev = -1.f;

#pragma unroll 1
    for (int it = 0; it < 100; ++it) {
        float p[8];
#pragma unroll
        for (int t = 0; t < 8; ++t) {
            floatx2 s2 = pk_mul(Mp[t][0], wv2[0]);
            s2 = pk_fma(Mp[t][1], wv2[1], s2);
            s2 = pk_fma(Mp[t][2], wv2[2], s2);
            s2 = pk_fma(Mp[t][3], wv2[3], s2);
            p[t] = s2[0] + s2[1];
        }
        p[0] += __shfl_xor(p[4], 4); p[1] += __shfl_xor(p[5], 4);
        p[2] += __shfl_xor(p[6], 4); p[3] += __shfl_xor(p[7], 4);
        p[0] += __shfl_xor(p[2], 2); p[1] += __shfl_xor(p[3], 2);
        p[0] += __shfl_xor(p[1], 1);
        float z_own = a_own * fast_rcp(p[0]);
        q8[0] = z_own;
        q8[1] = __shfl_xor(q8[0], 1);
        q8[2] = __shfl_xor(q8[0], 2); q8[3] = __shfl_xor(q8[1], 2);
        q8[4] = __shfl_xor(q8[0], 4); q8[5] = __shfl_xor(q8[1], 4);
        q8[6] = __shfl_xor(q8[2], 4); q8[7] = __shfl_xor(q8[3], 4);
        floatx2 c2[4];
#pragma unroll
        for (int j = 0; j < 4; ++j) {
            floatx2 qb0 = (floatx2){q8[0], q8[0]};
            c2[j] = pk_mul(Mp[0][j], qb0);
        }
#pragma unroll
        for (int t = 1; t < 8; ++t) {
            floatx2 qb = (floatx2){q8[t], q8[t]};
#pragma unroll
            for (int j = 0; j < 4; ++j)
                c2[j] = pk_fma(Mp[t][j], qb, c2[j]);
        }
        float cp[8];
#pragma unroll
        for (int j = 0; j < 4; ++j) { cp[2 * j] = c2[j][0]; cp[2 * j + 1] = c2[j][1]; }
        cp[0] += __shfl_xor(cp[4], 32); cp[1] += __shfl_xor(cp[5], 32);
        cp[2] += __shfl_xor(cp[6], 32); cp[3] += __shfl_xor(cp[7], 32);
        cp[0] += __shfl_xor(cp[2], 16); cp[1] += __shfl_xor(cp[3], 16);
        cp[0] += __shfl_xor(cp[1], 8);
        float w_own = b_own * fast_rcp(cp[0]);
        float w8_0 = w_own;
        float w8_1 = __shfl_xor(w8_0, 8);
        float w8_2 = __shfl_xor(w8_0, 16), w8_3 = __shfl_xor(w8_1, 16);
        float w8_4 = __shfl_xor(w8_0, 32), w8_5 = __shfl_xor(w8_1, 32);
        float w8_6 = __shfl_xor(w8_2, 32), w8_7 = __shfl_xor(w8_3, 32);
        wv2[0] = (floatx2){w8_0, w8_1};
        wv2[1] = (floatx2){w8_2, w8_3};
        wv2[2] = (floatx2){w8_4, w8_5};
        wv2[3] = (floatx2){w8_6, w8_7};
        // w stable across all 64 cols -> next z,w identical -> fixed point
        bool same = fabsf(w_own - w_prev) <= 1e-5f * w_own;
        w_prev = w_own;
        if (__all(same)) break;
    }

    // ---- phase 4: logits; sim = s0 + log2(M')*eps*ln2 ----
    float s = 0.f;
#pragma unroll
    for (int t = 0; t < 8; ++t)
#pragma unroll
        for (int c = 0; c < 8; ++c) {
            float m    = fmaxf(Mp[t][c >> 1][c & 1], 1e-30f);
            float sim  = fmaf(flog2(m), K_M2SIM, s0);
            float flow = q8[t] * m * wv2[c >> 1][c & 1];
            s = fmaf(sim, flow, s);
        }
    s += __shfl_xor(s, 1);  s += __shfl_xor(s, 2);  s += __shfl_xor(s, 4);
    s += __shfl_xor(s, 8);  s += __shfl_xor(s, 16); s += __shfl_xor(s, 32);
    if (lane == 0) out[gp] = s * 0.1953125f;   // 12.5/64
}

// ---------------------------------------------------------------------------
extern "C" void kernel_launch(void* const* d_in, const int* in_sizes, int n_in,
                              void* d_out, int out_size, void* d_ws, size_t ws_size,
                              hipStream_t stream) {
    (void)in_sizes; (void)n_in; (void)out_size; (void)ws_size;
    const float* support = (const float*)d_in[0];   // 32*512*64
    const float* query   = (const float*)d_in[1];   // 256*512*64

    char* ws = (char*)d_ws;
    _Float16* Uht  = (_Float16*)ws;                 // 16 MB (fragment order)
    _Float16* Vht  = Uht + 8388608;                 //  2 MB (fragment order)
    float* muA  = (float*)(Vht + 1048576);          // 72 KB [288][64]
    float* nrmA = muA + 18432;                      // 72 KB
    float* Ssc  = nrmA + 18432;                     // ~1 KB [288]  (~18.1 MB total)

    norm_kernel<<<288, 1024, 0, stream>>>(support, query, Vht, Uht,
                                          muA, nrmA, Ssc);
    emd_kernel<<<2048, 256, 0, stream>>>(Uht, Vht, muA, nrmA, Ssc,
                                         (float*)d_out);
}